// Round 1
// baseline (87.278 us; speedup 1.0000x reference)
//
#include <hip/hip_runtime.h>
#include <math.h>

// Problem constants (match reference)
#define B_ROWS 4096
#define D_DIM  512
#define N_ROWS 8192
#define R_NEG  4

// 1/(TEMPERATURE + EPSILON)
__device__ const float INV_T = (float)(1.0 / (0.5 + 1e-8));

// ---------------------------------------------------------------------------
// Kernel 1: inv_norm[i] = 1 / max(||z_i||, 1e-8)
// One wave (64 lanes) per row; 512 floats = 2 float4 per lane.
// ---------------------------------------------------------------------------
__global__ __launch_bounds__(256) void norms_kernel(
    const float* __restrict__ zi, const float* __restrict__ zj,
    float* __restrict__ inv_norm) {
  int wave = threadIdx.x >> 6;
  int lane = threadIdx.x & 63;
  int row  = blockIdx.x * 4 + wave;
  if (row >= N_ROWS) return;
  const float* z = (row < B_ROWS) ? (zi + (size_t)row * D_DIM)
                                  : (zj + (size_t)(row - B_ROWS) * D_DIM);
  const float4* z4 = (const float4*)z;
  float4 a = z4[lane];
  float4 b = z4[lane + 64];
  float s = a.x * a.x + a.y * a.y + a.z * a.z + a.w * a.w +
            b.x * b.x + b.y * b.y + b.z * b.z + b.w * b.w;
#pragma unroll
  for (int off = 32; off > 0; off >>= 1) s += __shfl_down(s, off);
  if (lane == 0) {
    inv_norm[row] = 1.0f / fmaxf(sqrtf(s), 1e-8f);
  }
}

// ---------------------------------------------------------------------------
// Kernel 2: per-row loss. One wave per row.
// logits = [sim(i, (i+B)%N), sim(i, cols[0..3])] / (T+eps)
// nll = -log_softmax(logits)[0]
// ---------------------------------------------------------------------------
__global__ __launch_bounds__(256) void loss_kernel(
    const float* __restrict__ zi, const float* __restrict__ zj,
    const int* __restrict__ neg_idx, const float* __restrict__ inv_norm,
    float* __restrict__ nll_out) {
  int wave = threadIdx.x >> 6;
  int lane = threadIdx.x & 63;
  int row  = blockIdx.x * 4 + wave;
  if (row >= N_ROWS) return;

  const float4* a4 =
      (row < B_ROWS) ? (const float4*)(zi + (size_t)row * D_DIM)
                     : (const float4*)(zj + (size_t)(row - B_ROWS) * D_DIM);
  float4 a0 = a4[lane];
  float4 a1 = a4[lane + 64];

  int cols[5];
  cols[0] = (row + B_ROWS) % N_ROWS;  // positive column
#pragma unroll
  for (int r = 0; r < R_NEG; ++r) {
    int k = neg_idx[row * R_NEG + r];      // in [0, N-1)
    cols[r + 1] = k + (k >= row ? 1 : 0);  // skip-diagonal mapping
  }

  float logits[5];
#pragma unroll
  for (int c = 0; c < 5; ++c) {
    int col = cols[c];
    const float4* b4 =
        (col < B_ROWS) ? (const float4*)(zi + (size_t)col * D_DIM)
                       : (const float4*)(zj + (size_t)(col - B_ROWS) * D_DIM);
    float4 b0 = b4[lane];
    float4 b1 = b4[lane + 64];
    float s = a0.x * b0.x + a0.y * b0.y + a0.z * b0.z + a0.w * b0.w +
              a1.x * b1.x + a1.y * b1.y + a1.z * b1.z + a1.w * b1.w;
#pragma unroll
    for (int off = 32; off > 0; off >>= 1) s += __shfl_down(s, off);
    logits[c] = s;  // valid in lane 0 only
  }

  if (lane == 0) {
    float inv_i = inv_norm[row];
    float m = -INFINITY;
#pragma unroll
    for (int c = 0; c < 5; ++c) {
      logits[c] *= inv_i * inv_norm[cols[c]] * INV_T;
      m = fmaxf(m, logits[c]);
    }
    float sum = 0.0f;
#pragma unroll
    for (int c = 0; c < 5; ++c) sum += __expf(logits[c] - m);
    float nll = -(logits[0] - m - __logf(sum));
    nll_out[row] = nll;
  }
}

// ---------------------------------------------------------------------------
// Kernel 3: reduce 8192 nll values -> mean -> d_out[0]
// Single block of 256 threads.
// ---------------------------------------------------------------------------
__global__ __launch_bounds__(256) void reduce_kernel(
    const float* __restrict__ nll, float* __restrict__ out) {
  __shared__ float smem[4];
  int lane = threadIdx.x & 63;
  int wave = threadIdx.x >> 6;
  float s = 0.0f;
  for (int i = threadIdx.x; i < N_ROWS; i += 256) s += nll[i];
#pragma unroll
  for (int off = 32; off > 0; off >>= 1) s += __shfl_down(s, off);
  if (lane == 0) smem[wave] = s;
  __syncthreads();
  if (threadIdx.x == 0) {
    float t = smem[0] + smem[1] + smem[2] + smem[3];
    out[0] = t * (1.0f / (float)N_ROWS);
  }
}

extern "C" void kernel_launch(void* const* d_in, const int* in_sizes, int n_in,
                              void* d_out, int out_size, void* d_ws,
                              size_t ws_size, hipStream_t stream) {
  const float* zi      = (const float*)d_in[0];
  const float* zj      = (const float*)d_in[1];
  const int*   neg_idx = (const int*)d_in[2];
  float* out = (float*)d_out;

  // Workspace layout: [0, N) inv_norm, [N, 2N) per-row nll
  float* inv_norm = (float*)d_ws;
  float* nll      = inv_norm + N_ROWS;

  dim3 block(256);
  dim3 grid(N_ROWS / 4);  // 4 waves per block, one wave per row

  norms_kernel<<<grid, block, 0, stream>>>(zi, zj, inv_norm);
  loss_kernel<<<grid, block, 0, stream>>>(zi, zj, neg_idx, inv_norm, nll);
  reduce_kernel<<<1, block, 0, stream>>>(nll, out);
}